// Round 16
// baseline (899.677 us; speedup 1.0000x reference)
//
#include <hip/hip_runtime.h>
#include <cstdint>
#include <cstddef>

namespace {

constexpr int DIMC  = 512;
constexpr int SEQ   = 6085;   // 1 CLS + 78*78
constexpr int NPAD  = 6144;   // padded to multiple of 256
constexpr int PADF  = 59;     // front zero-pad rows (NPAD - PADF == SEQ)
constexpr int LMK   = 256;    // landmarks
constexpr int BHN   = 16;     // B * HEADS
constexpr int KSP3  = 48;     // attn3 flash: one 128-wide KV tile per split
constexpr int MPADR = 6016;   // fc1 per-batch padded rows

typedef __attribute__((ext_vector_type(8))) short bf8_t;
typedef __attribute__((ext_vector_type(4))) float f4_t;

#define MFMA(a, b, c) __builtin_amdgcn_mfma_f32_16x16x32_bf16(a, b, c, 0, 0, 0)

// XOR-swizzle for [r][32 ushort] (64B-row) tiles — bijective (verified rounds 2-15)
#define SWZB(r, cu) (((((r) << 6) + ((cu) << 1))) ^ (((r) & 7) << 4))

#define GLDS16(gp, lp) __builtin_amdgcn_global_load_lds( \
    (const __attribute__((address_space(1))) void*)(gp), \
    (__attribute__((address_space(3))) void*)(lp), 16, 0, 0)

__device__ __forceinline__ ushort f2bf(float f) {
    union { float f; uint32_t u; } c{f};
    uint32_t u = c.u;
    return (ushort)((u + 0x7FFFu + ((u >> 16) & 1u)) >> 16);   // RNE
}
__device__ __forceinline__ float bf2f(ushort u) {
    union { uint32_t u; float f; } c{(uint32_t)u << 16};
    return c.f;
}

// ---------------- reduction helpers ----------------
__device__ __forceinline__ float waveSum(float v) {
#pragma unroll
    for (int o = 32; o > 0; o >>= 1) v += __shfl_xor(v, o, 64);
    return v;
}
__device__ __forceinline__ float waveMax(float v) {
#pragma unroll
    for (int o = 32; o > 0; o >>= 1) v = fmaxf(v, __shfl_xor(v, o, 64));
    return v;
}
__device__ __forceinline__ float blockSum256(float v, float* sm) {
    v = waveSum(v);
    __syncthreads();
    if ((threadIdx.x & 63) == 0) sm[threadIdx.x >> 6] = v;
    __syncthreads();
    return sm[0] + sm[1] + sm[2] + sm[3];
}
__device__ __forceinline__ float blockMax256(float v, float* sm) {
    v = waveMax(v);
    __syncthreads();
    if ((threadIdx.x & 63) == 0) sm[threadIdx.x >> 6] = v;
    __syncthreads();
    return fmaxf(fmaxf(sm[0], sm[1]), fmaxf(sm[2], sm[3]));
}
// 16-lane-group reductions
__device__ __forceinline__ float grpMax(float v) {
    v = fmaxf(v, __shfl_xor(v, 1, 64));
    v = fmaxf(v, __shfl_xor(v, 2, 64));
    v = fmaxf(v, __shfl_xor(v, 4, 64));
    v = fmaxf(v, __shfl_xor(v, 8, 64));
    return v;
}
__device__ __forceinline__ float grpSum(float v) {
    v += __shfl_xor(v, 1, 64);
    v += __shfl_xor(v, 2, 64);
    v += __shfl_xor(v, 4, 64);
    v += __shfl_xor(v, 8, 64);
    return v;
}

// =====================================================================
// Workhorse bf16 GEMM: C = A[M,K] @ B[N,K]^T. 128x128 tile, BK=64,
// global_load_lds(16B) pre-swizzled staging, bijective XCD block remap.
// EPI: 0 f32 out (+bias,+relu)  1 bf16 out  2 qkv split-scatter
//      3 residual: h[b][gm-PADF][gn] += acc + bias  (out-proj fused)
// =====================================================================
template<int EPI>
__global__ __launch_bounds__(256)
void gemm_bt(const ushort* __restrict__ A, const ushort* __restrict__ B,
             void* __restrict__ Cv, int M, int N, int K,
             int lda, int ldb, int ldc,
             long long sA, long long sB, long long sC,
             const float* __restrict__ bias, int relu,
             ushort* __restrict__ qp, ushort* __restrict__ kp, ushort* __restrict__ vp)
{
    __shared__ __align__(16) char As_s[128 * 128];
    __shared__ __align__(16) char Bs_s[128 * 128];
    // ---- bijective XCD-aware remap (m204) ----
    const int gx = gridDim.x, gy = gridDim.y;
    const int total = gx * gy * gridDim.z;
    int flat = (blockIdx.z * gy + blockIdx.y) * gx + blockIdx.x;
    {
        int q = total >> 3, r = total & 7;
        int xcd = flat & 7, idx = flat >> 3;
        flat = (xcd < r ? xcd * (q + 1) : r * (q + 1) + (xcd - r) * q) + idx;
    }
    const int z = flat / (gx * gy);
    const int rem = flat - z * gx * gy;
    const int by = rem / gx, bx = rem - by * gx;

    const ushort* Ab = A + (size_t)z * sA;
    const ushort* Bb = B + (size_t)z * sB;
    const int row0 = by * 128, col0 = bx * 128;
    const int tid = threadIdx.x, wid = tid >> 6, lane = tid & 63;
    const int wr = wid >> 1, wc = wid & 1, lr = lane & 15, kg = lane >> 4;
    const int srow = lane >> 3, sq = lane & 7;
    f4_t acc[4][4] = {};
    for (int k0 = 0; k0 < K; k0 += 64) {
        __syncthreads();
#pragma unroll
        for (int i = 0; i < 4; ++i) {
            int r = wid * 32 + i * 8 + srow;
            int qs = sq ^ (r & 7);
            GLDS16(Ab + (size_t)(row0 + r) * lda + k0 + qs * 8,
                   As_s + (wid * 32 + i * 8) * 128);
        }
#pragma unroll
        for (int i = 0; i < 4; ++i) {
            int r = wid * 32 + i * 8 + srow;
            int qs = sq ^ (r & 7);
            GLDS16(Bb + (size_t)(col0 + r) * ldb + k0 + qs * 8,
                   Bs_s + (wid * 32 + i * 8) * 128);
        }
        asm volatile("s_waitcnt vmcnt(0)" ::: "memory");
        __syncthreads();
#pragma unroll
        for (int ks = 0; ks < 2; ++ks) {
            bf8_t af[4], bg[4];
#pragma unroll
            for (int mr = 0; mr < 4; ++mr) {
                int r = wr * 64 + mr * 16 + lr;
                af[mr] = *(const bf8_t*)(As_s + r * 128 + ((((ks << 2) | kg) ^ (r & 7)) << 4));
            }
#pragma unroll
            for (int nr = 0; nr < 4; ++nr) {
                int r = wc * 64 + nr * 16 + lr;
                bg[nr] = *(const bf8_t*)(Bs_s + r * 128 + ((((ks << 2) | kg) ^ (r & 7)) << 4));
            }
#pragma unroll
            for (int mr = 0; mr < 4; ++mr)
#pragma unroll
                for (int nr = 0; nr < 4; ++nr)
                    acc[mr][nr] = MFMA(af[mr], bg[nr], acc[mr][nr]);
        }
    }
#pragma unroll
    for (int mr = 0; mr < 4; ++mr) {
#pragma unroll
        for (int nr = 0; nr < 4; ++nr) {
#pragma unroll
            for (int r = 0; r < 4; ++r) {
                int gm = row0 + wr * 64 + mr * 16 + kg * 4 + r;
                int gn = col0 + wc * 64 + nr * 16 + lr;
                if (gm >= M || gn >= N) continue;
                float val = acc[mr][nr][r];
                if (EPI == 0) {
                    if (bias) val += bias[gn];
                    if (relu) val = fmaxf(val, 0.f);
                    ((float*)Cv)[(size_t)z * sC + (size_t)gm * ldc + gn] = val;
                } else if (EPI == 1) {
                    ((ushort*)Cv)[(size_t)z * sC + (size_t)gm * ldc + gn] = f2bf(val);
                } else if (EPI == 2) {
                    int b = (gm >= NPAD) ? 1 : 0;
                    int i = gm - b * NPAD;
                    int which = gn >> 9, hh = (gn >> 6) & 7, d = gn & 63;
                    int bh = b * 8 + hh;
                    if (which == 0)
                        qp[((size_t)bh * NPAD + i) * 64 + d] = f2bf(val * 0.125f);
                    else if (which == 1)
                        kp[((size_t)bh * NPAD + i) * 64 + d] = f2bf(val);
                    else
                        vp[((size_t)bh * NPAD + i) * 64 + d] = f2bf(val);
                } else { // 3: residual add into h
                    int b = (gm >= NPAD) ? 1 : 0;
                    int i = gm - b * NPAD - PADF;
                    if (i >= 0) {
                        float* hp = (float*)Cv + ((size_t)(b * SEQ + i)) * DIMC + gn;
                        *hp += val + bias[gn];
                    }
                }
            }
        }
    }
}

// in [bh][NPAD][64] -> out [bh][64][NPAD]  (LDS 32x32 tiles, coalesced)
__global__ void transpose_v(const ushort* __restrict__ in, ushort* __restrict__ out) {
    __shared__ ushort tile[32][33];
    int bh = blockIdx.z;
    int r0 = blockIdx.x * 32, c0 = blockIdx.y * 32;
    const ushort* ib = in + (size_t)bh * NPAD * 64;
    ushort* ob = out + (size_t)bh * 64 * NPAD;
    int x = threadIdx.x, y = threadIdx.y;
    for (int yy = y; yy < 32; yy += 8)
        tile[yy][x] = ib[(size_t)(r0 + yy) * 64 + c0 + x];
    __syncthreads();
    for (int yy = y; yy < 32; yy += 8)
        ob[(size_t)(c0 + yy) * NPAD + r0 + x] = tile[x][yy];
}

// =====================================================================
// NS GEMM (K=256 fixed): C = alpha*(A @ Bt^T), both operands K-contiguous.
// SINGLE-SHOT staging (proven round 13). 64KB LDS.
// =====================================================================
template<int OC, int OCT, int CTD>
__global__ __launch_bounds__(256)
void gemm_nt(const ushort* __restrict__ A, const ushort* __restrict__ Bt,
             ushort* __restrict__ C, ushort* __restrict__ CT,
             float alpha, float cd, int ldC, int ldCT,
             long long sA, long long sBt, long long sC, long long sCT)
{
    __shared__ __align__(16) char As_s[64 * 512];
    __shared__ __align__(16) char Bs_s[64 * 512];
    const int z = blockIdx.z;
    const int row0 = blockIdx.y * 64, col0 = blockIdx.x * 64;
    const int tid = threadIdx.x, wid = tid >> 6, lane = tid & 63;
    const int lr = lane & 15, kg = lane >> 4;
    const ushort* Ab = A + (size_t)z * sA;
    const ushort* Bb = Bt + (size_t)z * sBt;
    const int srow8 = lane >> 5;
    const int sch = lane & 31;
#pragma unroll
    for (int i = 0; i < 8; ++i) {
        int rb = i * 8 + wid * 2 + srow8;
        int qs = sch ^ (rb & 7);
        GLDS16(Ab + (size_t)(row0 + rb) * 256 + qs * 8,
               As_s + (i * 8 + wid * 2) * 512);
    }
#pragma unroll
    for (int i = 0; i < 8; ++i) {
        int rb = i * 8 + wid * 2 + srow8;
        int qs = sch ^ (rb & 7);
        GLDS16(Bb + (size_t)(col0 + rb) * 256 + qs * 8,
               Bs_s + (i * 8 + wid * 2) * 512);
    }
    asm volatile("s_waitcnt vmcnt(0)" ::: "memory");
    __syncthreads();
    f4_t acc[4] = {};
    const int arow = wid * 16 + lr;
#pragma unroll
    for (int ks = 0; ks < 8; ++ks) {
        bf8_t af = *(const bf8_t*)(As_s + arow * 512 + (((ks * 4 + kg) ^ (arow & 7)) << 4));
#pragma unroll
        for (int j = 0; j < 4; ++j) {
            int brow = j * 16 + lr;
            bf8_t bg = *(const bf8_t*)(Bs_s + brow * 512 + (((ks * 4 + kg) ^ (brow & 7)) << 4));
            acc[j] = MFMA(af, bg, acc[j]);
        }
    }
#pragma unroll
    for (int j = 0; j < 4; ++j) {
#pragma unroll
        for (int r = 0; r < 4; ++r) {
            int gm = row0 + wid * 16 + kg * 4 + r;
            int gn = col0 + j * 16 + lr;
            float val = alpha * acc[j][r];
            if (OC) C[(size_t)z * sC + (size_t)gm * ldC + gn] = f2bf(val);
            if (OCT) CT[(size_t)z * sCT + (size_t)gn * ldCT + gm] =
                f2bf(CTD ? (((gm == gn) ? cd : 0.f) - val) : val);
        }
    }
}

// =====================================================================
// Flash attn3, single KV tile per block (validated round 9):
// partial softmax(q_l @ k^T) @ v over one 128-wide KV slice; per-tile
// softmax, P in per-wave LDS (no barriers), LSE stats out.
// grid (KSP3=48, 2, BHN).
// =====================================================================
__global__ __launch_bounds__(256)
void pv_flash(const ushort* __restrict__ ql, const ushort* __restrict__ k,
              const ushort* __restrict__ vT, float* __restrict__ o2p,
              float* __restrict__ lmb, float* __restrict__ lsb)
{
    __shared__ __align__(16) char P_s[128 * 256];   // 128 rows x 128 bf16 = 32KB
    const int split = blockIdx.x, mt = blockIdx.y, bh = blockIdx.z;
    const int tid = threadIdx.x, wid = tid >> 6, lane = tid & 63;
    const int lr = lane & 15, kg = lane >> 4;
    const int rowb = wid * 32;
    const ushort* qlb = ql + ((size_t)bh * LMK + mt * 128) * 64;
    const ushort* kb  = k  + (size_t)bh * NPAD * 64;
    const ushort* vTb = vT + (size_t)bh * 64 * NPAD;
    const int kvb = split * 128;

    // ---- S = ql_tile(128) @ k_tile(128)^T ----
    f4_t sacc[2][8] = {};
#pragma unroll
    for (int ks = 0; ks < 2; ++ks) {
        bf8_t af[2];
#pragma unroll
        for (int mf = 0; mf < 2; ++mf)
            af[mf] = *(const bf8_t*)&qlb[(size_t)(rowb + mf * 16 + lr) * 64 + ks * 32 + kg * 8];
#pragma unroll
        for (int nf = 0; nf < 8; ++nf) {
            bf8_t bg = *(const bf8_t*)&kb[(size_t)(kvb + nf * 16 + lr) * 64 + ks * 32 + kg * 8];
            sacc[0][nf] = MFMA(af[0], bg, sacc[0][nf]);
            sacc[1][nf] = MFMA(af[1], bg, sacc[1][nf]);
        }
    }
    // ---- per-tile softmax (16-lane groups), P -> per-wave LDS ----
    float mloc[2][4], lloc[2][4];
#pragma unroll
    for (int mf = 0; mf < 2; ++mf) {
        float tmax[4] = {-3.0e38f, -3.0e38f, -3.0e38f, -3.0e38f};
#pragma unroll
        for (int nf = 0; nf < 8; ++nf)
#pragma unroll
            for (int r = 0; r < 4; ++r) tmax[r] = fmaxf(tmax[r], sacc[mf][nf][r]);
#pragma unroll
        for (int r = 0; r < 4; ++r) { tmax[r] = grpMax(tmax[r]); mloc[mf][r] = tmax[r]; }
        float lsum[4] = {0.f, 0.f, 0.f, 0.f};
        const int rb2 = rowb + mf * 16 + kg * 4;
        const int cc2 = (lr & 7) * 2, chi = lr >> 3;
#pragma unroll
        for (int nf = 0; nf < 8; ++nf)
#pragma unroll
            for (int r = 0; r < 4; ++r) {
                float e = __expf(sacc[mf][nf][r] - tmax[r]);
                lsum[r] += e;
                int row = rb2 + r;
                int chunk = (2 * nf + chi) ^ (row & 7);
                *(ushort*)(P_s + row * 256 + chunk * 16 + cc2) = f2bf(e);
            }
#pragma unroll
        for (int r = 0; r < 4; ++r) lloc[mf][r] = grpSum(lsum[r]);
    }
    // ---- PV: acco = P_tile @ v_tile (K=128, vT 16B direct reads) ----
    f4_t acco[2][4] = {};
#pragma unroll
    for (int kt2 = 0; kt2 < 4; ++kt2) {
        bf8_t af2[2];
#pragma unroll
        for (int mf = 0; mf < 2; ++mf) {
            int row = rowb + mf * 16 + lr;
            int chunk = (kt2 * 4 + kg) ^ (row & 7);
            af2[mf] = *(const bf8_t*)(P_s + row * 256 + chunk * 16);
        }
#pragma unroll
        for (int nf2 = 0; nf2 < 4; ++nf2) {
            bf8_t bg = *(const bf8_t*)&vTb[(size_t)(nf2 * 16 + lr) * NPAD + kvb + kt2 * 32 + kg * 8];
            acco[0][nf2] = MFMA(af2[0], bg, acco[0][nf2]);
            acco[1][nf2] = MFMA(af2[1], bg, acco[1][nf2]);
        }
    }
    // ---- write unnormalized partials + stats ----
#pragma unroll
    for (int mf = 0; mf < 2; ++mf)
#pragma unroll
        for (int nf2 = 0; nf2 < 4; ++nf2)
#pragma unroll
            for (int r = 0; r < 4; ++r) {
                int gm = mt * 128 + rowb + mf * 16 + kg * 4 + r;
                o2p[((size_t)(split * BHN + bh) * LMK + gm) * 64 + nf2 * 16 + lr] = acco[mf][nf2][r];
            }
    if (lr == 0) {
#pragma unroll
        for (int mf = 0; mf < 2; ++mf)
#pragma unroll
            for (int r = 0; r < 4; ++r) {
                int gm = mt * 128 + rowb + mf * 16 + kg * 4 + r;
                lmb[(size_t)(split * BHN + bh) * LMK + gm] = mloc[mf][r];
                lsb[(size_t)(split * BHN + bh) * LMK + gm] = lloc[mf][r];
            }
    }
}

// LSE-weighted merge of the KV splits -> o2t[bh][64][256] (transposed)
__global__ void reduce_o2(const float* __restrict__ o2p, const float* __restrict__ lmb,
                          const float* __restrict__ lsb, ushort* __restrict__ o2t)
{
    int idx = blockIdx.x * 256 + threadIdx.x;   // < BHN*LMK*64
    int bh = idx >> 14, m = (idx >> 6) & 255, d = idx & 63;
    float gm = -3.0e38f;
#pragma unroll 8
    for (int s = 0; s < KSP3; ++s)
        gm = fmaxf(gm, lmb[(size_t)(s * BHN + bh) * LMK + m]);
    float num = 0.f, den = 0.f;
#pragma unroll 4
    for (int s = 0; s < KSP3; ++s) {
        float wgt = __expf(lmb[(size_t)(s * BHN + bh) * LMK + m] - gm);
        num += wgt * o2p[((size_t)(s * BHN + bh) << 14) + (m << 6) + d];
        den += wgt * lsb[(size_t)(s * BHN + bh) * LMK + m];
    }
    o2t[((size_t)bh * 64 + d) * 256 + m] = f2bf(num / den);
}

// =====================================================================
// Fused attn1 (64-row tiles, proven rounds 8-15): S=q@kl^T ->
// in-register softmax -> P to per-wave LDS -> out = P@W, normalized in
// epilogue, scattered to ot. No __syncthreads. grid (96, BHN).
// =====================================================================
__global__ __launch_bounds__(256)
void attn1_fused(const ushort* __restrict__ q, const ushort* __restrict__ kl,
                 const ushort* __restrict__ Wt, ushort* __restrict__ ot)
{
    __shared__ __align__(16) char P_s[64 * 512];   // 32KB
    const int mt = blockIdx.x;       // 0..95
    const int bh = blockIdx.y;       // 0..15
    const int b = bh >> 3, hh = bh & 7;
    const int tid = threadIdx.x, wid = tid >> 6, lane = tid & 63;
    const int lr = lane & 15, kg = lane >> 4;
    const int row0 = mt * 64, rowb = wid * 16;
    const ushort* qb  = q  + (size_t)bh * NPAD * 64;
    const ushort* klb = kl + (size_t)bh * LMK * 64;
    const ushort* Wtb = Wt + (size_t)bh * 128 * 256;

    f4_t acc[16];
#pragma unroll
    for (int nf = 0; nf < 16; ++nf) acc[nf] = (f4_t){0.f, 0.f, 0.f, 0.f};
#pragma unroll
    for (int ks = 0; ks < 2; ++ks) {
        bf8_t af = *(const bf8_t*)&qb[(size_t)(row0 + rowb + lr) * 64 + ks * 32 + kg * 8];
#pragma unroll
        for (int nf = 0; nf < 16; ++nf) {
            bf8_t bg = *(const bf8_t*)&klb[(size_t)(nf * 16 + lr) * 64 + ks * 32 + kg * 8];
            acc[nf] = MFMA(af, bg, acc[nf]);
        }
    }
    float inv_s[4];
    {
        float mx[4] = {-3.0e38f, -3.0e38f, -3.0e38f, -3.0e38f};
#pragma unroll
        for (int nf = 0; nf < 16; ++nf)
#pragma unroll
            for (int r = 0; r < 4; ++r) mx[r] = fmaxf(mx[r], acc[nf][r]);
#pragma unroll
        for (int r = 0; r < 4; ++r) mx[r] = grpMax(mx[r]);
        float sum[4] = {0.f, 0.f, 0.f, 0.f};
        const int rb2 = rowb + kg * 4;
        const int cc2 = (lr & 7) * 2, chi = lr >> 3;
#pragma unroll
        for (int nf = 0; nf < 16; ++nf)
#pragma unroll
            for (int r = 0; r < 4; ++r) {
                float e = __expf(acc[nf][r] - mx[r]);
                sum[r] += e;
                int row = rb2 + r;
                int chunk = (2 * nf + chi) ^ (row & 7);
                *(ushort*)(P_s + row * 512 + chunk * 16 + cc2) = f2bf(e);
            }
#pragma unroll
        for (int r = 0; r < 4; ++r) inv_s[r] = 1.f / grpSum(sum[r]);
    }
    f4_t acc2[4] = {};
#pragma unroll
    for (int kt = 0; kt < 8; ++kt) {
        int row = rowb + lr;
        int chunk = (kt * 4 + kg) ^ (row & 7);
        bf8_t af2 = *(const bf8_t*)(P_s + row * 512 + chunk * 16);
#pragma unroll
        for (int nf = 0; nf < 4; ++nf) {
            bf8_t bg = *(const bf8_t*)&Wtb[(size_t)(nf * 16 + lr) * 256 + kt * 32 + kg * 8];
            acc2[nf] = MFMA(af2, bg, acc2[nf]);
        }
    }
#pragma unroll
    for (int nf = 0; nf < 4; ++nf)
#pragma unroll
        for (int r = 0; r < 4; ++r) {
            int gm = row0 + rowb + kg * 4 + r;
            int gn = nf * 16 + lr;
            ot[((size_t)(b * NPAD + gm)) * DIMC + hh * 64 + gn] = f2bf(acc2[nf][r] * inv_s[r]);
        }
}

// ---------------- small kernels ----------------
__global__ void cvt_bf16(const float* __restrict__ in, ushort* __restrict__ out, int n8) {
    int i = blockIdx.x * 256 + threadIdx.x;
    if (i >= n8) return;
    float4 a = ((const float4*)in)[i * 2], b = ((const float4*)in)[i * 2 + 1];
    ushort4 lo = { f2bf(a.x), f2bf(a.y), f2bf(a.z), f2bf(a.w) };
    ushort4 hi = { f2bf(b.x), f2bf(b.y), f2bf(b.z), f2bf(b.w) };
    ((ushort4*)out)[i * 2] = lo;
    ((ushort4*)out)[i * 2 + 1] = hi;
}

__global__ void extend_h(float* __restrict__ h, const float* __restrict__ cls) {
    int b = blockIdx.y, bx = blockIdx.x;
    float* hb = h + (size_t)b * SEQ * DIMC;
    for (int c = threadIdx.x; c < DIMC; c += 256) {
        if (bx == 0) hb[c] = cls[c];
        else hb[(size_t)(6000 + bx) * DIMC + c] = hb[(size_t)bx * DIMC + c];
    }
}

__global__ void zero_xp_pad(ushort* __restrict__ xp) {
    int e = blockIdx.x * 256 + threadIdx.x;
    int b = e / (PADF * DIMC);
    int rest = e - b * (PADF * DIMC);
    xp[(size_t)b * NPAD * DIMC + rest] = 0;
}

__global__ __launch_bounds__(128)
void ln_to_xp(const float* __restrict__ h, const float* __restrict__ g,
              const float* __restrict__ bb, ushort* __restrict__ xp)
{
    __shared__ float sm[2];
    int r = blockIdx.x;
    int b = r / SEQ, i = r - b * SEQ;
    int t = threadIdx.x;
    const float4* row = (const float4*)(h + (size_t)r * DIMC);
    float4 x = row[t];
    float s  = x.x + x.y + x.z + x.w;
    float sq = x.x * x.x + x.y * x.y + x.z * x.z + x.w * x.w;
    s = waveSum(s);
    sq = waveSum(sq);
    int w = t >> 6;
    if ((t & 63) == 0) sm[w] = s;
    __syncthreads();
    float S = sm[0] + sm[1];
    __syncthreads();
    if ((t & 63) == 0) sm[w] = sq;
    __syncthreads();
    float SQ = sm[0] + sm[1];
    float mu = S * (1.f / DIMC);
    float var = SQ * (1.f / DIMC) - mu * mu;
    float rs = rsqrtf(var + 1e-5f);
    float4 gg = ((const float4*)g)[t];
    float4 bv = ((const float4*)bb)[t];
    ushort4 o;
    o.x = f2bf((x.x - mu) * rs * gg.x + bv.x);
    o.y = f2bf((x.y - mu) * rs * gg.y + bv.y);
    o.z = f2bf((x.z - mu) * rs * gg.z + bv.z);
    o.w = f2bf((x.w - mu) * rs * gg.w + bv.w);
    ((ushort4*)(xp + ((size_t)b * NPAD + PADF + i) * DIMC))[t] = o;
}

__global__ void landmark_mean(const ushort* __restrict__ in, ushort* __restrict__ out) {
    int m = blockIdx.x, bh = blockIdx.y, d = threadIdx.x;
    const ushort* p = in + ((size_t)bh * NPAD + (size_t)m * (NPAD / LMK)) * 64 + d;
    float s = 0.f;
#pragma unroll
    for (int j = 0; j < NPAD / LMK; ++j) s += bf2f(p[(size_t)j * 64]);
    out[((size_t)bh * LMK + m) * 64 + d] = f2bf(s * (1.f / (NPAD / LMK)));
}

__global__ __launch_bounds__(256)
void softmax_bf256(ushort* __restrict__ S) {     // bf16, rows of 256
    __shared__ float sm[4];
    ushort* p = S + (size_t)blockIdx.x * 256;
    int t = threadIdx.x;
    float v = bf2f(p[t]);
    float bm = blockMax256(v, sm);
    float e = __expf(v - bm);
    float bs = blockSum256(e, sm);
    p[t] = f2bf(e / bs);
}

// max over (bh, j) of column sums of X; 16 blocks -> 16 atomics
__global__ __launch_bounds__(256)
void colsum_max(const ushort* __restrict__ X, float* __restrict__ scal) {
    __shared__ float sm[4];
    int bh = blockIdx.x, t = threadIdx.x;
    const ushort* Xb = X + ((size_t)bh << 16);
    float s = 0.f;
#pragma unroll 8
    for (int i = 0; i < 256; ++i) s += bf2f(Xb[(size_t)i * 256 + t]);
    float m = blockMax256(s, sm);
    if (t == 0) atomicMax((unsigned int*)scal, __float_as_uint(m));
}

// Z = X^T/s (row-major iterate), Zt = X/s (= Z^T, B operand for gemm_nt)
__global__ void init_z(const ushort* __restrict__ X, const float* __restrict__ scal,
                       ushort* __restrict__ Z, ushort* __restrict__ Zt) {
    size_t e = (size_t)blockIdx.x * 256 + threadIdx.x;
    int c = (int)(e & 255);
    int r = (int)((e >> 8) & 255);
    size_t bh = e >> 16;
    float inv = 1.f / scal[0];
    Z[e]  = f2bf(bf2f(X[(bh << 16) + (size_t)c * 256 + r]) * inv);
    Zt[e] = f2bf(bf2f(X[e]) * inv);
}

// depthwise conv residual (v row-major, proven rounds 4-15)
__global__ __launch_bounds__(256)
void conv_add(const ushort* __restrict__ v, const float* __restrict__ cw,
              ushort* __restrict__ ot)
{
    __shared__ float w[33];
    __shared__ ushort vt[96][64];
    int bh = blockIdx.y;
    int b = bh >> 3, hh = bh & 7;
    int i0 = blockIdx.x * 64;
    int t = threadIdx.x;
    if (t < 33) w[t] = cw[hh * 33 + t];
    const ushort* vb = v + (size_t)bh * NPAD * 64;
    int d = t & 63;
    for (int rr = t >> 6; rr < 96; rr += 4) {
        int j = i0 - 16 + rr;
        vt[rr][d] = (j >= 0 && j < NPAD) ? vb[(size_t)j * 64 + d] : (ushort)0;
    }
    __syncthreads();
    for (int ii = t >> 6; ii < 64; ii += 4) {
        float acc = 0.f;
#pragma unroll
        for (int kk = 0; kk < 33; ++kk) acc += w[kk] * bf2f(vt[ii + kk][d]);
        size_t off = ((size_t)(b * NPAD + i0 + ii)) * DIMC + hh * 64 + d;
        ot[off] = f2bf(bf2f(ot[off]) + acc);
    }
}

__global__ __launch_bounds__(256)
void final_head(const float* __restrict__ h, const float* __restrict__ g,
                const float* __restrict__ bb, const float* __restrict__ w2,
                const float* __restrict__ b2, float* __restrict__ out)
{
    __shared__ float row[DIMC];
    __shared__ float sm[4];
    int b = blockIdx.x;
    int t = threadIdx.x;
    const float* x = h + (size_t)b * SEQ * DIMC;
    float v0 = x[t], v1 = x[t + 256];
    float S = blockSum256(v0 + v1, sm);
    float SQ = blockSum256(v0 * v0 + v1 * v1, sm);
    float mu = S * (1.f / DIMC);
    float rs = rsqrtf(SQ * (1.f / DIMC) - mu * mu + 1e-5f);
    row[t] = (v0 - mu) * rs * g[t] + bb[t];
    row[t + 256] = (v1 - mu) * rs * g[t + 256] + bb[t + 256];
    __syncthreads();
    if (t < 64) {
        float a0 = 0.f, a1 = 0.f;
        for (int idx = t; idx < DIMC; idx += 64) {
            a0 += row[idx] * w2[idx];
            a1 += row[idx] * w2[DIMC + idx];
        }
        a0 = waveSum(a0);
        a1 = waveSum(a1);
        if (t == 0) {
            out[b * 2 + 0] = a0 + b2[0];
            out[b * 2 + 1] = a1 + b2[1];
        }
    }
}

// ---------------- host helpers ----------------
void bt(int epi, const ushort* A, const ushort* B, void* C, int M, int N, int K,
        int lda, int ldb, int ldc, long long sA, long long sB, long long sC, int batch,
        const float* bias, int relu, ushort* qp, ushort* kp, ushort* vp, hipStream_t s)
{
    dim3 g((N + 127) / 128, (M + 127) / 128, batch), blk(256);
    switch (epi) {
    case 0: gemm_bt<0><<<g, blk, 0, s>>>(A, B, C, M, N, K, lda, ldb, ldc, sA, sB, sC, bias, relu, qp, kp, vp); break;
    case 1: gemm_bt<1><<<g, blk, 0, s>>>(A, B, C, M, N, K, lda, ldb, ldc, sA, sB, sC, bias, relu, qp, kp, vp); break;
    case 2: gemm_bt<2><<<g, blk, 0, s>>>(A, B, C, M, N, K, lda, ldb, ldc, sA, sB, sC, bias, relu, qp, kp, vp); break;
    default: gemm_bt<3><<<g, blk, 0, s>>>(A, B, C, M, N, K, lda, ldb, ldc, sA, sB, sC, bias, relu, qp, kp, vp); break;
    }
}

// mode 0: C+CT(diag)   1: CT(diag) only   2: C+CT   3: CT only
void nt(int mode, const ushort* A, const ushort* Bt, ushort* C, ushort* CT,
        float alpha, float cd, int M, int N, int ldC, int ldCT,
        long long sA, long long sBt, long long sC, long long sCT, hipStream_t s)
{
    dim3 g(N / 64, M / 64, BHN), blk(256);
    switch (mode) {
    case 0: gemm_nt<1, 1, 1><<<g, blk, 0, s>>>(A, Bt, C, CT, alpha, cd, ldC, ldCT, sA, sBt, sC, sCT); break;
    case 1: gemm_nt<0, 1, 1><<<g, blk, 0, s>>>(A, Bt, C, CT, alpha, cd, ldC, ldCT, sA, sBt, sC, sCT); break;
    case 2: gemm_nt<1, 1, 0><<<g, blk, 0, s>>>(A, Bt, C, CT, alpha, cd, ldC, ldCT, sA, sBt, sC, sCT); break;
    default: gemm_nt<0, 1, 0><<<g, blk, 0, s>>>(A, Bt, C, CT, alpha, cd, ldC, ldCT, sA, sBt, sC, sCT); break;
    }
}

struct WS {
    float *h, *scal, *o2p, *lmb, *lsb;
    ushort *xp, *q, *k, *v, *vT, *ql, *kl;
    ushort *datab, *w1b, *qkvwb1, *qkvwb2, *outwb1, *outwb2;
    ushort *X, *Y, *TAt, *TBt, *Z0, *Z0t, *Z1, *Z1t;
    ushort *o2t, *Wt, *ot;
};

void nystrom_layer(float* h, const float* lng, const float* lnb,
                   const ushort* qkvwb, const ushort* outwb, const float* outb,
                   const float* convw, const WS& w, hipStream_t s)
{
    const long long SM = (long long)LMK * LMK;
    // LN -> padded xp (bf16)
    zero_xp_pad<<<(2 * PADF * DIMC) / 256, 256, 0, s>>>(w.xp);
    ln_to_xp<<<2 * SEQ, 128, 0, s>>>(h, lng, lnb, w.xp);
    // qkv: fused split-scatter into q (scaled), k, v
    bt(2, w.xp, qkvwb, nullptr, 2 * NPAD, 3 * DIMC, DIMC, DIMC, DIMC, 0,
       0, 0, 0, 1, nullptr, 0, w.q, w.k, w.v, s);
    transpose_v<<<dim3(NPAD / 32, 2, BHN), dim3(32, 8), 0, s>>>(w.v, w.vT);
    landmark_mean<<<dim3(LMK, BHN), 64, 0, s>>>(w.q, w.ql);
    landmark_mean<<<dim3(LMK, BHN), 64, 0, s>>>(w.k, w.kl);
    // attn2 = softmax(q_l @ k_l^T) -> X bf16
    bt(1, w.ql, w.kl, w.X, LMK, LMK, 64, 64, 64, LMK,
       (long long)LMK * 64, (long long)LMK * 64, SM, BHN,
       nullptr, 0, nullptr, nullptr, nullptr, s);
    softmax_bf256<<<BHN * LMK, 256, 0, s>>>(w.X);
    hipMemsetAsync(w.scal, 0, 8, s);
    colsum_max<<<BHN, 256, 0, s>>>(w.X, w.scal);
    init_z<<<(BHN * LMK * LMK) / 256, 256, 0, s>>>(w.X, w.scal, w.Z0, w.Z0t);
    // Newton-Schulz, transpose-carried, single-shot-staged GEMMs
    ushort *Zc = w.Z0, *Zct = w.Z0t, *Zn = w.Z1, *Znt = w.Z1t;
    for (int it = 0; it < 6; ++it) {
        nt(0, w.X, Zct, w.Y, w.TAt, 1.f, 7.f, LMK, LMK, 256, 256, SM, SM, SM, SM, s);
        nt(1, w.Y, w.TAt, nullptr, w.TBt, 1.f, 15.f, LMK, LMK, 256, 256, SM, SM, 0, SM, s);
        nt(1, w.Y, w.TBt, nullptr, w.TAt, 1.f, 13.f, LMK, LMK, 256, 256, SM, SM, 0, SM, s);
        nt(2, Zc, w.TAt, Zn, Znt, 0.25f, 0.f, LMK, LMK, 256, 256, SM, SM, SM, SM, s);
        ushort* t;
        t = Zc; Zc = Zn; Zn = t;
        t = Zct; Zct = Znt; Znt = t;
    }
    // ---- attn3: flash (single-tile splits) + LSE merge ----
    pv_flash<<<dim3(KSP3, 2, BHN), 256, 0, s>>>(w.ql, w.k, w.vT, w.o2p, w.lmb, w.lsb);
    reduce_o2<<<BHN * LMK * 64 / 256, 256, 0, s>>>(w.o2p, w.lmb, w.lsb, w.o2t);
    // Wt = (Zc @ o2)^T  (CT-only gemm_nt; Wt bh stride 128*256)
    nt(3, Zc, w.o2t, nullptr, w.Wt, 1.f, 0.f, LMK, 64, 256, 256,
       SM, 64 * 256, 0, 128 * 256, s);
    // ---- attn1 fused: softmax(q @ k_l^T) @ W -> ot ----
    attn1_fused<<<dim3(NPAD / 64, BHN), 256, 0, s>>>(w.q, w.kl, w.Wt, w.ot);
    // + depthwise conv(v)
    conv_add<<<dim3(NPAD / 64, BHN), 256, 0, s>>>(w.v, convw, w.ot);
    // out proj with fused residual: h += ot @ outw^T + outb
    bt(3, w.ot, outwb, h, 2 * NPAD, DIMC, DIMC, DIMC, DIMC, 0,
       0, 0, 0, 1, outb, 0, nullptr, nullptr, nullptr, s);
}

} // namespace

extern "C" void kernel_launch(void* const* d_in, const int* in_sizes, int n_in,
                              void* d_out, int out_size, void* d_ws, size_t ws_size,
                              hipStream_t stream)
{
    (void)in_sizes; (void)n_in; (void)out_size;
    const float* data  = (const float*)d_in[0];
    const float* w1    = (const float*)d_in[1];
    const float* b1    = (const float*)d_in[2];
    const float* cls   = (const float*)d_in[3];
    const float* ln1g  = (const float*)d_in[4];
    const float* ln1b  = (const float*)d_in[5];
    const float* qkv1w = (const float*)d_in[6];
    const float* out1w = (const float*)d_in[7];
    const float* out1b = (const float*)d_in[8];
    const float* conv1 = (const float*)d_in[9];
    const float* ln2g  = (const float*)d_in[10];
    const float* ln2b  = (const float*)d_in[11];
    const float* qkv2w = (const float*)d_in[12];
    const float* out2w = (const float*)d_in[13];
    const float* out2b = (const float*)d_in[14];
    const float* conv2 = (const float*)d_in[15];
    const float* lnfg  = (const float*)d_in[16];
    const float* lnfb  = (const float*)d_in[17];
    const float* w2    = (const float*)d_in[18];
    const float* b2    = (const float*)d_in[19];
    float* out = (float*)d_out;

    if (ws_size < 209473792ull) return;
    char* p = (char*)d_ws;
    auto alloc = [&](size_t bytes) { char* r = p; p += (bytes + 255) & ~(size_t)255; return r; };
    WS w;
    w.h     = (float*)alloc((size_t)2 * SEQ * DIMC * 4);
    w.xp    = (ushort*)alloc((size_t)2 * NPAD * DIMC * 2);
    w.q     = (ushort*)alloc((size_t)BHN * NPAD * 64 * 2);
    w.k     = (ushort*)alloc((size_t)BHN * NPAD * 64 * 2);   // ot overlay
    w.v     = (ushort*)alloc((size_t)BHN * NPAD * 64 * 2);
    w.vT    = (ushort*)alloc((size_t)BHN * 64 * NPAD * 2);
    w.ql    = (ushort*)alloc((size_t)BHN * LMK * 64 * 2);
    w.kl    = (ushort*)alloc((size_t)BHN * LMK * 64 * 2);
    w.scal  = (float*)alloc(256);
    w.lmb   = (float*)alloc((size_t)KSP3 * BHN * LMK * 4);
    w.lsb   = (float*)alloc((size_t)KSP3 * BHN * LMK * 4);
    w.datab = (ushort*)alloc((size_t)2 * MPADR * 1024 * 2);
    w.w1b   = (ushort*)alloc((size_t)512 * 1024 * 2);
    w.qkvwb1= (ushort*)alloc((size_t)1536 * 512 * 2);
    w.qkvwb2= (ushort*)alloc((size_t)1536 * 512 * 2);
    w.outwb1= (ushort*)alloc((size_t)512 * 512 * 2);
    w.outwb2= (ushort*)alloc((size_t)512 * 512 * 2);
    w.X     = (ushort*)alloc((size_t)BHN * LMK * LMK * 2);
    w.Y     = (ushort*)alloc((size_t)BHN * LMK * LMK * 2);
    w.TAt   = (ushort*)alloc((size_t)BHN * LMK * LMK * 2);
    w.TBt   = (ushort*)alloc((size_t)BHN * LMK * LMK * 2);
    w.Z0    = (ushort*)alloc((size_t)BHN * LMK * LMK * 2);
    w.Z0t   = (ushort*)alloc((size_t)BHN * LMK * LMK * 2);
    w.Z1    = (ushort*)alloc((size_t)BHN * LMK * LMK * 2);
    w.Z1t   = (ushort*)alloc((size_t)BHN * LMK * LMK * 2);
    w.o2p   = (float*)alloc((size_t)KSP3 * BHN * LMK * 64 * 4);   // 50.3 MB
    w.o2t   = (ushort*)alloc((size_t)BHN * 64 * 256 * 2);
    w.Wt    = (ushort*)alloc((size_t)BHN * 128 * 256 * 2);
    w.ot    = w.k;           // ot overlays k (k dead after pv_flash)

    // ---- one-time per-call bf16 conversions ----
    for (int b = 0; b < 2; ++b)
        cvt_bf16<<<3000, 256, 0, stream>>>(data + (size_t)b * 6000 * 1024,
                                           w.datab + (size_t)b * MPADR * 1024, 768000);
    cvt_bf16<<<256, 256, 0, stream>>>(w1, w.w1b, 65536);
    cvt_bf16<<<384, 256, 0, stream>>>(qkv1w, w.qkvwb1, 98304);
    cvt_bf16<<<384, 256, 0, stream>>>(qkv2w, w.qkvwb2, 98304);
    cvt_bf16<<<128, 256, 0, stream>>>(out1w, w.outwb1, 32768);
    cvt_bf16<<<128, 256, 0, stream>>>(out2w, w.outwb2, 32768);

    // fc1: h[b, 1+i, :] = relu(data[b,i,:] @ w1^T + b1)
    bt(0, w.datab, w.w1b, w.h + DIMC, 6000, DIMC, 1024, 1024, 1024, DIMC,
       (long long)MPADR * 1024, 0, (long long)SEQ * DIMC, 2, b1, 1,
       nullptr, nullptr, nullptr, stream);
    extend_h<<<dim3(85, 2), 256, 0, stream>>>(w.h, cls);

    nystrom_layer(w.h, ln1g, ln1b, w.qkvwb1, w.outwb1, out1b, conv1, w, stream);
    nystrom_layer(w.h, ln2g, ln2b, w.qkvwb2, w.outwb2, out2b, conv2, w, stream);

    final_head<<<2, 256, 0, stream>>>(w.h, lnfg, lnfb, w2, b2, out);
}

// Round 17
// 879.831 us; speedup vs baseline: 1.0226x; 1.0226x over previous
//
#include <hip/hip_runtime.h>
#include <cstdint>
#include <cstddef>

namespace {

constexpr int DIMC  = 512;
constexpr int SEQ   = 6085;   // 1 CLS + 78*78
constexpr int NPAD  = 6144;   // padded to multiple of 256
constexpr int PADF  = 59;     // front zero-pad rows (NPAD - PADF == SEQ)
constexpr int LMK   = 256;    // landmarks
constexpr int BHN   = 16;     // B * HEADS
constexpr int KSPL  = 16;     // split-K factor for attn3 PV
constexpr int MPADR = 6016;   // fc1 per-batch padded rows

typedef __attribute__((ext_vector_type(8))) short bf8_t;
typedef __attribute__((ext_vector_type(4))) float f4_t;

#define MFMA(a, b, c) __builtin_amdgcn_mfma_f32_16x16x32_bf16(a, b, c, 0, 0, 0)

// XOR-swizzle for [r][32 ushort] (64B-row) tiles — bijective (verified rounds 2-15)
#define SWZB(r, cu) (((((r) << 6) + ((cu) << 1))) ^ (((r) & 7) << 4))

#define GLDS16(gp, lp) __builtin_amdgcn_global_load_lds( \
    (const __attribute__((address_space(1))) void*)(gp), \
    (__attribute__((address_space(3))) void*)(lp), 16, 0, 0)

__device__ __forceinline__ ushort f2bf(float f) {
    union { float f; uint32_t u; } c{f};
    uint32_t u = c.u;
    return (ushort)((u + 0x7FFFu + ((u >> 16) & 1u)) >> 16);   // RNE
}
__device__ __forceinline__ float bf2f(ushort u) {
    union { uint32_t u; float f; } c{(uint32_t)u << 16};
    return c.f;
}

// ---------------- reduction helpers ----------------
__device__ __forceinline__ float waveSum(float v) {
#pragma unroll
    for (int o = 32; o > 0; o >>= 1) v += __shfl_xor(v, o, 64);
    return v;
}
__device__ __forceinline__ float waveMax(float v) {
#pragma unroll
    for (int o = 32; o > 0; o >>= 1) v = fmaxf(v, __shfl_xor(v, o, 64));
    return v;
}
__device__ __forceinline__ float blockSum256(float v, float* sm) {
    v = waveSum(v);
    __syncthreads();
    if ((threadIdx.x & 63) == 0) sm[threadIdx.x >> 6] = v;
    __syncthreads();
    return sm[0] + sm[1] + sm[2] + sm[3];
}
__device__ __forceinline__ float blockMax256(float v, float* sm) {
    v = waveMax(v);
    __syncthreads();
    if ((threadIdx.x & 63) == 0) sm[threadIdx.x >> 6] = v;
    __syncthreads();
    return fmaxf(fmaxf(sm[0], sm[1]), fmaxf(sm[2], sm[3]));
}
// 16-lane-group reductions
__device__ __forceinline__ float grpMax(float v) {
    v = fmaxf(v, __shfl_xor(v, 1, 64));
    v = fmaxf(v, __shfl_xor(v, 2, 64));
    v = fmaxf(v, __shfl_xor(v, 4, 64));
    v = fmaxf(v, __shfl_xor(v, 8, 64));
    return v;
}
__device__ __forceinline__ float grpSum(float v) {
    v += __shfl_xor(v, 1, 64);
    v += __shfl_xor(v, 2, 64);
    v += __shfl_xor(v, 4, 64);
    v += __shfl_xor(v, 8, 64);
    return v;
}

// =====================================================================
// Workhorse bf16 GEMM: C = A[M,K] @ B[N,K]^T. 128x128 tile, BK=64,
// global_load_lds(16B) pre-swizzled staging, bijective XCD block remap.
// EPI: 0 f32 out (+bias,+relu)  1 bf16 out  2 qkv split-scatter
//      3 residual: h[b][gm-PADF][gn] += acc + bias  (out-proj fused)
// =====================================================================
template<int EPI>
__global__ __launch_bounds__(256)
void gemm_bt(const ushort* __restrict__ A, const ushort* __restrict__ B,
             void* __restrict__ Cv, int M, int N, int K,
             int lda, int ldb, int ldc,
             long long sA, long long sB, long long sC,
             const float* __restrict__ bias, int relu,
             ushort* __restrict__ qp, ushort* __restrict__ kp, ushort* __restrict__ vp)
{
    __shared__ __align__(16) char As_s[128 * 128];
    __shared__ __align__(16) char Bs_s[128 * 128];
    // ---- bijective XCD-aware remap (m204) ----
    const int gx = gridDim.x, gy = gridDim.y;
    const int total = gx * gy * gridDim.z;
    int flat = (blockIdx.z * gy + blockIdx.y) * gx + blockIdx.x;
    {
        int q = total >> 3, r = total & 7;
        int xcd = flat & 7, idx = flat >> 3;
        flat = (xcd < r ? xcd * (q + 1) : r * (q + 1) + (xcd - r) * q) + idx;
    }
    const int z = flat / (gx * gy);
    const int rem = flat - z * gx * gy;
    const int by = rem / gx, bx = rem - by * gx;

    const ushort* Ab = A + (size_t)z * sA;
    const ushort* Bb = B + (size_t)z * sB;
    const int row0 = by * 128, col0 = bx * 128;
    const int tid = threadIdx.x, wid = tid >> 6, lane = tid & 63;
    const int wr = wid >> 1, wc = wid & 1, lr = lane & 15, kg = lane >> 4;
    const int srow = lane >> 3, sq = lane & 7;
    f4_t acc[4][4] = {};
    for (int k0 = 0; k0 < K; k0 += 64) {
        __syncthreads();
#pragma unroll
        for (int i = 0; i < 4; ++i) {
            int r = wid * 32 + i * 8 + srow;
            int qs = sq ^ (r & 7);
            GLDS16(Ab + (size_t)(row0 + r) * lda + k0 + qs * 8,
                   As_s + (wid * 32 + i * 8) * 128);
        }
#pragma unroll
        for (int i = 0; i < 4; ++i) {
            int r = wid * 32 + i * 8 + srow;
            int qs = sq ^ (r & 7);
            GLDS16(Bb + (size_t)(col0 + r) * ldb + k0 + qs * 8,
                   Bs_s + (wid * 32 + i * 8) * 128);
        }
        asm volatile("s_waitcnt vmcnt(0)" ::: "memory");
        __syncthreads();
#pragma unroll
        for (int ks = 0; ks < 2; ++ks) {
            bf8_t af[4], bg[4];
#pragma unroll
            for (int mr = 0; mr < 4; ++mr) {
                int r = wr * 64 + mr * 16 + lr;
                af[mr] = *(const bf8_t*)(As_s + r * 128 + ((((ks << 2) | kg) ^ (r & 7)) << 4));
            }
#pragma unroll
            for (int nr = 0; nr < 4; ++nr) {
                int r = wc * 64 + nr * 16 + lr;
                bg[nr] = *(const bf8_t*)(Bs_s + r * 128 + ((((ks << 2) | kg) ^ (r & 7)) << 4));
            }
#pragma unroll
            for (int mr = 0; mr < 4; ++mr)
#pragma unroll
                for (int nr = 0; nr < 4; ++nr)
                    acc[mr][nr] = MFMA(af[mr], bg[nr], acc[mr][nr]);
        }
    }
#pragma unroll
    for (int mr = 0; mr < 4; ++mr) {
#pragma unroll
        for (int nr = 0; nr < 4; ++nr) {
#pragma unroll
            for (int r = 0; r < 4; ++r) {
                int gm = row0 + wr * 64 + mr * 16 + kg * 4 + r;
                int gn = col0 + wc * 64 + nr * 16 + lr;
                if (gm >= M || gn >= N) continue;
                float val = acc[mr][nr][r];
                if (EPI == 0) {
                    if (bias) val += bias[gn];
                    if (relu) val = fmaxf(val, 0.f);
                    ((float*)Cv)[(size_t)z * sC + (size_t)gm * ldc + gn] = val;
                } else if (EPI == 1) {
                    ((ushort*)Cv)[(size_t)z * sC + (size_t)gm * ldc + gn] = f2bf(val);
                } else if (EPI == 2) {
                    int b = (gm >= NPAD) ? 1 : 0;
                    int i = gm - b * NPAD;
                    int which = gn >> 9, hh = (gn >> 6) & 7, d = gn & 63;
                    int bh = b * 8 + hh;
                    if (which == 0)
                        qp[((size_t)bh * NPAD + i) * 64 + d] = f2bf(val * 0.125f);
                    else if (which == 1)
                        kp[((size_t)bh * NPAD + i) * 64 + d] = f2bf(val);
                    else
                        vp[((size_t)bh * NPAD + i) * 64 + d] = f2bf(val);
                } else { // 3: residual add into h
                    int b = (gm >= NPAD) ? 1 : 0;
                    int i = gm - b * NPAD - PADF;
                    if (i >= 0) {
                        float* hp = (float*)Cv + ((size_t)(b * SEQ + i)) * DIMC + gn;
                        *hp += val + bias[gn];
                    }
                }
            }
        }
    }
}

// in [bh][NPAD][64] -> out [bh][64][NPAD]  (LDS 32x32 tiles, coalesced)
__global__ void transpose_v(const ushort* __restrict__ in, ushort* __restrict__ out) {
    __shared__ ushort tile[32][33];
    int bh = blockIdx.z;
    int r0 = blockIdx.x * 32, c0 = blockIdx.y * 32;
    const ushort* ib = in + (size_t)bh * NPAD * 64;
    ushort* ob = out + (size_t)bh * 64 * NPAD;
    int x = threadIdx.x, y = threadIdx.y;
    for (int yy = y; yy < 32; yy += 8)
        tile[yy][x] = ib[(size_t)(r0 + yy) * 64 + c0 + x];
    __syncthreads();
    for (int yy = y; yy < 32; yy += 8)
        ob[(size_t)(c0 + yy) * NPAD + r0 + x] = tile[x][yy];
}

// =====================================================================
// NS GEMM (K=256 fixed): C = alpha*(A @ Bt^T), both operands K-contiguous.
// SINGLE-SHOT staging (proven round 13). 64KB LDS.
// =====================================================================
template<int OC, int OCT, int CTD>
__global__ __launch_bounds__(256)
void gemm_nt(const ushort* __restrict__ A, const ushort* __restrict__ Bt,
             ushort* __restrict__ C, ushort* __restrict__ CT,
             float alpha, float cd, int ldC, int ldCT,
             long long sA, long long sBt, long long sC, long long sCT)
{
    __shared__ __align__(16) char As_s[64 * 512];
    __shared__ __align__(16) char Bs_s[64 * 512];
    const int z = blockIdx.z;
    const int row0 = blockIdx.y * 64, col0 = blockIdx.x * 64;
    const int tid = threadIdx.x, wid = tid >> 6, lane = tid & 63;
    const int lr = lane & 15, kg = lane >> 4;
    const ushort* Ab = A + (size_t)z * sA;
    const ushort* Bb = Bt + (size_t)z * sBt;
    const int srow8 = lane >> 5;
    const int sch = lane & 31;
#pragma unroll
    for (int i = 0; i < 8; ++i) {
        int rb = i * 8 + wid * 2 + srow8;
        int qs = sch ^ (rb & 7);
        GLDS16(Ab + (size_t)(row0 + rb) * 256 + qs * 8,
               As_s + (i * 8 + wid * 2) * 512);
    }
#pragma unroll
    for (int i = 0; i < 8; ++i) {
        int rb = i * 8 + wid * 2 + srow8;
        int qs = sch ^ (rb & 7);
        GLDS16(Bb + (size_t)(col0 + rb) * 256 + qs * 8,
               Bs_s + (i * 8 + wid * 2) * 512);
    }
    asm volatile("s_waitcnt vmcnt(0)" ::: "memory");
    __syncthreads();
    f4_t acc[4] = {};
    const int arow = wid * 16 + lr;
#pragma unroll
    for (int ks = 0; ks < 8; ++ks) {
        bf8_t af = *(const bf8_t*)(As_s + arow * 512 + (((ks * 4 + kg) ^ (arow & 7)) << 4));
#pragma unroll
        for (int j = 0; j < 4; ++j) {
            int brow = j * 16 + lr;
            bf8_t bg = *(const bf8_t*)(Bs_s + brow * 512 + (((ks * 4 + kg) ^ (brow & 7)) << 4));
            acc[j] = MFMA(af, bg, acc[j]);
        }
    }
#pragma unroll
    for (int j = 0; j < 4; ++j) {
#pragma unroll
        for (int r = 0; r < 4; ++r) {
            int gm = row0 + wid * 16 + kg * 4 + r;
            int gn = col0 + j * 16 + lr;
            float val = alpha * acc[j][r];
            if (OC) C[(size_t)z * sC + (size_t)gm * ldC + gn] = f2bf(val);
            if (OCT) CT[(size_t)z * sCT + (size_t)gn * ldCT + gm] =
                f2bf(CTD ? (((gm == gn) ? cd : 0.f) - val) : val);
        }
    }
}

// per-row stats of S: lm = row max, li = 1/sum(exp(s - lm)).  grid BHN*LMK.
__global__ __launch_bounds__(256)
void row_stats(const ushort* __restrict__ S, float* __restrict__ lm,
               float* __restrict__ li)
{
    __shared__ float sm[4];
    const ushort* p = S + (size_t)blockIdx.x * NPAD;
    int t = threadIdx.x;
    float v[24];
    float mx = -1e30f;
#pragma unroll
    for (int j = 0; j < 24; ++j) { v[j] = bf2f(p[j * 256 + t]); mx = fmaxf(mx, v[j]); }
    float bm = blockMax256(mx, sm);
    float s = 0.f;
#pragma unroll
    for (int j = 0; j < 24; ++j) s += __expf(v[j] - bm);
    float bs = blockSum256(s, sm);
    if (t == 0) { lm[blockIdx.x] = bm; li[blockIdx.x] = 1.f / bs; }
}

// =====================================================================
// attn3 PV split-K with inline softmax (proven rounds 14-15).
// =====================================================================
__global__ __launch_bounds__(256)
void pv_splitk(const ushort* __restrict__ S, const ushort* __restrict__ vT,
               const float* __restrict__ lm, const float* __restrict__ li,
               float* __restrict__ o2p)
{
    __shared__ __align__(16) char As_s[128 * 64];
    __shared__ __align__(16) char Bs_s[64 * 64];
    __shared__ float smax[128], sinv[128];
    const int split = blockIdx.x, mt = blockIdx.y, bh = blockIdx.z;
    const int tid = threadIdx.x;
    const int wid = tid >> 6, lane = tid & 63;
    const int lr = lane & 15, kg = lane >> 4;
    const ushort* Sb = S + (size_t)bh * LMK * NPAD + (size_t)(mt * 128) * NPAD;
    const ushort* vTb = vT + (size_t)bh * 64 * NPAD;
    const int ks0 = split * (NPAD / KSPL);
    if (tid < 128) {
        smax[tid] = lm[bh * LMK + mt * 128 + tid];
        sinv[tid] = li[bh * LMK + mt * 128 + tid];
    }
    __syncthreads();
    f4_t acc[2][4] = {};
    for (int k0 = ks0; k0 < ks0 + NPAD / KSPL; k0 += 32) {
#pragma unroll
        for (int p = 0; p < 2; ++p) {
            int idx = p * 256 + tid;
            int m = idx >> 2, kc = (idx & 3) * 8;
            bf8_t raw = *(const bf8_t*)&Sb[(size_t)m * NPAD + k0 + kc];
            float mr = smax[m], iv = sinv[m];
            bf8_t o;
#pragma unroll
            for (int j = 0; j < 8; ++j)
                o[j] = (short)f2bf(__expf(bf2f((ushort)raw[j]) - mr) * iv);
            *(bf8_t*)(As_s + SWZB(m, kc)) = o;
        }
        {
            int n = tid >> 2, kc = (tid & 3) * 8;
            *(bf8_t*)(Bs_s + SWZB(n, kc)) = *(const bf8_t*)&vTb[(size_t)n * NPAD + k0 + kc];
        }
        __syncthreads();
        bf8_t af[2], bg[4];
#pragma unroll
        for (int i = 0; i < 2; ++i)
            af[i] = *(const bf8_t*)(As_s + SWZB(wid * 32 + i * 16 + lr, kg * 8));
#pragma unroll
        for (int j = 0; j < 4; ++j)
            bg[j] = *(const bf8_t*)(Bs_s + SWZB(j * 16 + lr, kg * 8));
#pragma unroll
        for (int i = 0; i < 2; ++i)
#pragma unroll
            for (int j = 0; j < 4; ++j)
                acc[i][j] = MFMA(af[i], bg[j], acc[i][j]);
        __syncthreads();
    }
#pragma unroll
    for (int i = 0; i < 2; ++i)
#pragma unroll
        for (int j = 0; j < 4; ++j)
#pragma unroll
            for (int r = 0; r < 4; ++r) {
                int gm = mt * 128 + wid * 32 + i * 16 + kg * 4 + r;
                int gn = j * 16 + lr;
                o2p[((size_t)(split * BHN + bh) * LMK + gm) * 64 + gn] = acc[i][j][r];
            }
}

// sum splits -> o2t[bh][64][256] (transposed: B operand for the Wt GEMM)
__global__ void reduce_o2(const float* __restrict__ o2p, ushort* __restrict__ o2t) {
    int idx = blockIdx.x * 256 + threadIdx.x;   // < BHN*LMK*64
    int bh = idx >> 14, m = (idx >> 6) & 255, d = idx & 63;
    float s = 0.f;
#pragma unroll
    for (int sp = 0; sp < KSPL; ++sp)
        s += o2p[((size_t)(sp * BHN + bh) << 14) + (m << 6) + d];
    o2t[((size_t)bh * 64 + d) * 256 + m] = f2bf(s);
}

// =====================================================================
// Fused attn1 (64-row tiles, proven rounds 8-15): S=q@kl^T ->
// in-register softmax -> P to per-wave LDS -> out = P@W, normalized in
// epilogue, scattered to ot. No __syncthreads. grid (96, BHN).
// =====================================================================
__global__ __launch_bounds__(256)
void attn1_fused(const ushort* __restrict__ q, const ushort* __restrict__ kl,
                 const ushort* __restrict__ Wt, ushort* __restrict__ ot)
{
    __shared__ __align__(16) char P_s[64 * 512];   // 32KB
    const int mt = blockIdx.x;       // 0..95
    const int bh = blockIdx.y;       // 0..15
    const int b = bh >> 3, hh = bh & 7;
    const int tid = threadIdx.x, wid = tid >> 6, lane = tid & 63;
    const int lr = lane & 15, kg = lane >> 4;
    const int row0 = mt * 64, rowb = wid * 16;
    const ushort* qb  = q  + (size_t)bh * NPAD * 64;
    const ushort* klb = kl + (size_t)bh * LMK * 64;
    const ushort* Wtb = Wt + (size_t)bh * 128 * 256;

    f4_t acc[16];
#pragma unroll
    for (int nf = 0; nf < 16; ++nf) acc[nf] = (f4_t){0.f, 0.f, 0.f, 0.f};
#pragma unroll
    for (int ks = 0; ks < 2; ++ks) {
        bf8_t af = *(const bf8_t*)&qb[(size_t)(row0 + rowb + lr) * 64 + ks * 32 + kg * 8];
#pragma unroll
        for (int nf = 0; nf < 16; ++nf) {
            bf8_t bg = *(const bf8_t*)&klb[(size_t)(nf * 16 + lr) * 64 + ks * 32 + kg * 8];
            acc[nf] = MFMA(af, bg, acc[nf]);
        }
    }
    float inv_s[4];
    {
        float mx[4] = {-3.0e38f, -3.0e38f, -3.0e38f, -3.0e38f};
#pragma unroll
        for (int nf = 0; nf < 16; ++nf)
#pragma unroll
            for (int r = 0; r < 4; ++r) mx[r] = fmaxf(mx[r], acc[nf][r]);
#pragma unroll
        for (int r = 0; r < 4; ++r) mx[r] = grpMax(mx[r]);
        float sum[4] = {0.f, 0.f, 0.f, 0.f};
        const int rb2 = rowb + kg * 4;
        const int cc2 = (lr & 7) * 2, chi = lr >> 3;
#pragma unroll
        for (int nf = 0; nf < 16; ++nf)
#pragma unroll
            for (int r = 0; r < 4; ++r) {
                float e = __expf(acc[nf][r] - mx[r]);
                sum[r] += e;
                int row = rb2 + r;
                int chunk = (2 * nf + chi) ^ (row & 7);
                *(ushort*)(P_s + row * 512 + chunk * 16 + cc2) = f2bf(e);
            }
#pragma unroll
        for (int r = 0; r < 4; ++r) inv_s[r] = 1.f / grpSum(sum[r]);
    }
    f4_t acc2[4] = {};
#pragma unroll
    for (int kt = 0; kt < 8; ++kt) {
        int row = rowb + lr;
        int chunk = (kt * 4 + kg) ^ (row & 7);
        bf8_t af2 = *(const bf8_t*)(P_s + row * 512 + chunk * 16);
#pragma unroll
        for (int nf = 0; nf < 4; ++nf) {
            bf8_t bg = *(const bf8_t*)&Wtb[(size_t)(nf * 16 + lr) * 256 + kt * 32 + kg * 8];
            acc2[nf] = MFMA(af2, bg, acc2[nf]);
        }
    }
#pragma unroll
    for (int nf = 0; nf < 4; ++nf)
#pragma unroll
        for (int r = 0; r < 4; ++r) {
            int gm = row0 + rowb + kg * 4 + r;
            int gn = nf * 16 + lr;
            ot[((size_t)(b * NPAD + gm)) * DIMC + hh * 64 + gn] = f2bf(acc2[nf][r] * inv_s[r]);
        }
}

// ---------------- small kernels ----------------
__global__ void cvt_bf16(const float* __restrict__ in, ushort* __restrict__ out, int n8) {
    int i = blockIdx.x * 256 + threadIdx.x;
    if (i >= n8) return;
    float4 a = ((const float4*)in)[i * 2], b = ((const float4*)in)[i * 2 + 1];
    ushort4 lo = { f2bf(a.x), f2bf(a.y), f2bf(a.z), f2bf(a.w) };
    ushort4 hi = { f2bf(b.x), f2bf(b.y), f2bf(b.z), f2bf(b.w) };
    ((ushort4*)out)[i * 2] = lo;
    ((ushort4*)out)[i * 2 + 1] = hi;
}

__global__ void extend_h(float* __restrict__ h, const float* __restrict__ cls) {
    int b = blockIdx.y, bx = blockIdx.x;
    float* hb = h + (size_t)b * SEQ * DIMC;
    for (int c = threadIdx.x; c < DIMC; c += 256) {
        if (bx == 0) hb[c] = cls[c];
        else hb[(size_t)(6000 + bx) * DIMC + c] = hb[(size_t)bx * DIMC + c];
    }
}

__global__ void zero_xp_pad(ushort* __restrict__ xp) {
    int e = blockIdx.x * 256 + threadIdx.x;
    int b = e / (PADF * DIMC);
    int rest = e - b * (PADF * DIMC);
    xp[(size_t)b * NPAD * DIMC + rest] = 0;
}

__global__ __launch_bounds__(128)
void ln_to_xp(const float* __restrict__ h, const float* __restrict__ g,
              const float* __restrict__ bb, ushort* __restrict__ xp)
{
    __shared__ float sm[2];
    int r = blockIdx.x;
    int b = r / SEQ, i = r - b * SEQ;
    int t = threadIdx.x;
    const float4* row = (const float4*)(h + (size_t)r * DIMC);
    float4 x = row[t];
    float s  = x.x + x.y + x.z + x.w;
    float sq = x.x * x.x + x.y * x.y + x.z * x.z + x.w * x.w;
    s = waveSum(s);
    sq = waveSum(sq);
    int w = t >> 6;
    if ((t & 63) == 0) sm[w] = s;
    __syncthreads();
    float S = sm[0] + sm[1];
    __syncthreads();
    if ((t & 63) == 0) sm[w] = sq;
    __syncthreads();
    float SQ = sm[0] + sm[1];
    float mu = S * (1.f / DIMC);
    float var = SQ * (1.f / DIMC) - mu * mu;
    float rs = rsqrtf(var + 1e-5f);
    float4 gg = ((const float4*)g)[t];
    float4 bv = ((const float4*)bb)[t];
    ushort4 o;
    o.x = f2bf((x.x - mu) * rs * gg.x + bv.x);
    o.y = f2bf((x.y - mu) * rs * gg.y + bv.y);
    o.z = f2bf((x.z - mu) * rs * gg.z + bv.z);
    o.w = f2bf((x.w - mu) * rs * gg.w + bv.w);
    ((ushort4*)(xp + ((size_t)b * NPAD + PADF + i) * DIMC))[t] = o;
}

// landmark means for q and k in one launch: blockIdx.z selects source/dest
__global__ void landmark_mean2(const ushort* __restrict__ q, const ushort* __restrict__ k,
                               ushort* __restrict__ ql, ushort* __restrict__ kl)
{
    int m = blockIdx.x, bh = blockIdx.y, d = threadIdx.x;
    const ushort* in = (blockIdx.z == 0) ? q : k;
    ushort* out = (blockIdx.z == 0) ? ql : kl;
    const ushort* p = in + ((size_t)bh * NPAD + (size_t)m * (NPAD / LMK)) * 64 + d;
    float s = 0.f;
#pragma unroll
    for (int j = 0; j < NPAD / LMK; ++j) s += bf2f(p[(size_t)j * 64]);
    out[((size_t)bh * LMK + m) * 64 + d] = f2bf(s * (1.f / (NPAD / LMK)));
}

__global__ __launch_bounds__(256)
void softmax_bf256(ushort* __restrict__ S) {     // bf16, rows of 256
    __shared__ float sm[4];
    ushort* p = S + (size_t)blockIdx.x * 256;
    int t = threadIdx.x;
    float v = bf2f(p[t]);
    float bm = blockMax256(v, sm);
    float e = __expf(v - bm);
    float bs = blockSum256(e, sm);
    p[t] = f2bf(e / bs);
}

// max over (bh, j) of column sums of X; 16 blocks -> 16 atomics
__global__ __launch_bounds__(256)
void colsum_max(const ushort* __restrict__ X, float* __restrict__ scal) {
    __shared__ float sm[4];
    int bh = blockIdx.x, t = threadIdx.x;
    const ushort* Xb = X + ((size_t)bh << 16);
    float s = 0.f;
#pragma unroll 8
    for (int i = 0; i < 256; ++i) s += bf2f(Xb[(size_t)i * 256 + t]);
    float m = blockMax256(s, sm);
    if (t == 0) atomicMax((unsigned int*)scal, __float_as_uint(m));
}

// Z = X^T/s (row-major iterate), Zt = X/s (= Z^T, B operand for gemm_nt)
__global__ void init_z(const ushort* __restrict__ X, const float* __restrict__ scal,
                       ushort* __restrict__ Z, ushort* __restrict__ Zt) {
    size_t e = (size_t)blockIdx.x * 256 + threadIdx.x;
    int c = (int)(e & 255);
    int r = (int)((e >> 8) & 255);
    size_t bh = e >> 16;
    float inv = 1.f / scal[0];
    Z[e]  = f2bf(bf2f(X[(bh << 16) + (size_t)c * 256 + r]) * inv);
    Zt[e] = f2bf(bf2f(X[e]) * inv);
}

// depthwise conv residual (v row-major, proven rounds 4-15)
__global__ __launch_bounds__(256)
void conv_add(const ushort* __restrict__ v, const float* __restrict__ cw,
              ushort* __restrict__ ot)
{
    __shared__ float w[33];
    __shared__ ushort vt[96][64];
    int bh = blockIdx.y;
    int b = bh >> 3, hh = bh & 7;
    int i0 = blockIdx.x * 64;
    int t = threadIdx.x;
    if (t < 33) w[t] = cw[hh * 33 + t];
    const ushort* vb = v + (size_t)bh * NPAD * 64;
    int d = t & 63;
    for (int rr = t >> 6; rr < 96; rr += 4) {
        int j = i0 - 16 + rr;
        vt[rr][d] = (j >= 0 && j < NPAD) ? vb[(size_t)j * 64 + d] : (ushort)0;
    }
    __syncthreads();
    for (int ii = t >> 6; ii < 64; ii += 4) {
        float acc = 0.f;
#pragma unroll
        for (int kk = 0; kk < 33; ++kk) acc += w[kk] * bf2f(vt[ii + kk][d]);
        size_t off = ((size_t)(b * NPAD + i0 + ii)) * DIMC + hh * 64 + d;
        ot[off] = f2bf(bf2f(ot[off]) + acc);
    }
}

__global__ __launch_bounds__(256)
void final_head(const float* __restrict__ h, const float* __restrict__ g,
                const float* __restrict__ bb, const float* __restrict__ w2,
                const float* __restrict__ b2, float* __restrict__ out)
{
    __shared__ float row[DIMC];
    __shared__ float sm[4];
    int b = blockIdx.x;
    int t = threadIdx.x;
    const float* x = h + (size_t)b * SEQ * DIMC;
    float v0 = x[t], v1 = x[t + 256];
    float S = blockSum256(v0 + v1, sm);
    float SQ = blockSum256(v0 * v0 + v1 * v1, sm);
    float mu = S * (1.f / DIMC);
    float rs = rsqrtf(SQ * (1.f / DIMC) - mu * mu + 1e-5f);
    row[t] = (v0 - mu) * rs * g[t] + bb[t];
    row[t + 256] = (v1 - mu) * rs * g[t + 256] + bb[t + 256];
    __syncthreads();
    if (t < 64) {
        float a0 = 0.f, a1 = 0.f;
        for (int idx = t; idx < DIMC; idx += 64) {
            a0 += row[idx] * w2[idx];
            a1 += row[idx] * w2[DIMC + idx];
        }
        a0 = waveSum(a0);
        a1 = waveSum(a1);
        if (t == 0) {
            out[b * 2 + 0] = a0 + b2[0];
            out[b * 2 + 1] = a1 + b2[1];
        }
    }
}

// ---------------- host helpers ----------------
void bt(int epi, const ushort* A, const ushort* B, void* C, int M, int N, int K,
        int lda, int ldb, int ldc, long long sA, long long sB, long long sC, int batch,
        const float* bias, int relu, ushort* qp, ushort* kp, ushort* vp, hipStream_t s)
{
    dim3 g((N + 127) / 128, (M + 127) / 128, batch), blk(256);
    switch (epi) {
    case 0: gemm_bt<0><<<g, blk, 0, s>>>(A, B, C, M, N, K, lda, ldb, ldc, sA, sB, sC, bias, relu, qp, kp, vp); break;
    case 1: gemm_bt<1><<<g, blk, 0, s>>>(A, B, C, M, N, K, lda, ldb, ldc, sA, sB, sC, bias, relu, qp, kp, vp); break;
    case 2: gemm_bt<2><<<g, blk, 0, s>>>(A, B, C, M, N, K, lda, ldb, ldc, sA, sB, sC, bias, relu, qp, kp, vp); break;
    default: gemm_bt<3><<<g, blk, 0, s>>>(A, B, C, M, N, K, lda, ldb, ldc, sA, sB, sC, bias, relu, qp, kp, vp); break;
    }
}

// mode 0: C+CT(diag)   1: CT(diag) only   2: C+CT   3: CT only
void nt(int mode, const ushort* A, const ushort* Bt, ushort* C, ushort* CT,
        float alpha, float cd, int M, int N, int ldC, int ldCT,
        long long sA, long long sBt, long long sC, long long sCT, hipStream_t s)
{
    dim3 g(N / 64, M / 64, BHN), blk(256);
    switch (mode) {
    case 0: gemm_nt<1, 1, 1><<<g, blk, 0, s>>>(A, Bt, C, CT, alpha, cd, ldC, ldCT, sA, sBt, sC, sCT); break;
    case 1: gemm_nt<0, 1, 1><<<g, blk, 0, s>>>(A, Bt, C, CT, alpha, cd, ldC, ldCT, sA, sBt, sC, sCT); break;
    case 2: gemm_nt<1, 1, 0><<<g, blk, 0, s>>>(A, Bt, C, CT, alpha, cd, ldC, ldCT, sA, sBt, sC, sCT); break;
    default: gemm_nt<0, 1, 0><<<g, blk, 0, s>>>(A, Bt, C, CT, alpha, cd, ldC, ldCT, sA, sBt, sC, sCT); break;
    }
}

struct WS {
    float *h, *scal, *o2p, *lm, *li;
    ushort *xp, *q, *k, *v, *vT, *ql, *kl;
    ushort *datab, *w1b, *qkvwb1, *qkvwb2, *outwb1, *outwb2;
    ushort *X, *Y, *TAt, *TBt, *Z0, *Z0t, *Z1, *Z1t;
    ushort *o2t, *Wt, *S, *ot;
};

void nystrom_layer(float* h, const float* lng, const float* lnb,
                   const ushort* qkvwb, const ushort* outwb, const float* outb,
                   const float* convw, const WS& w, hipStream_t s)
{
    const long long SM = (long long)LMK * LMK;
    // LN -> padded xp (bf16)
    zero_xp_pad<<<(2 * PADF * DIMC) / 256, 256, 0, s>>>(w.xp);
    ln_to_xp<<<2 * SEQ, 128, 0, s>>>(h, lng, lnb, w.xp);
    // qkv: fused split-scatter into q (scaled), k, v
    bt(2, w.xp, qkvwb, nullptr, 2 * NPAD, 3 * DIMC, DIMC, DIMC, DIMC, 0,
       0, 0, 0, 1, nullptr, 0, w.q, w.k, w.v, s);
    transpose_v<<<dim3(NPAD / 32, 2, BHN), dim3(32, 8), 0, s>>>(w.v, w.vT);
    landmark_mean2<<<dim3(LMK, BHN, 2), 64, 0, s>>>(w.q, w.k, w.ql, w.kl);
    // attn2 = softmax(q_l @ k_l^T) -> X bf16
    bt(1, w.ql, w.kl, w.X, LMK, LMK, 64, 64, 64, LMK,
       (long long)LMK * 64, (long long)LMK * 64, SM, BHN,
       nullptr, 0, nullptr, nullptr, nullptr, s);
    softmax_bf256<<<BHN * LMK, 256, 0, s>>>(w.X);
    hipMemsetAsync(w.scal, 0, 8, s);
    colsum_max<<<BHN, 256, 0, s>>>(w.X, w.scal);
    init_z<<<(BHN * LMK * LMK) / 256, 256, 0, s>>>(w.X, w.scal, w.Z0, w.Z0t);
    // Newton-Schulz, transpose-carried, single-shot-staged GEMMs
    ushort *Zc = w.Z0, *Zct = w.Z0t, *Zn = w.Z1, *Znt = w.Z1t;
    for (int it = 0; it < 6; ++it) {
        nt(0, w.X, Zct, w.Y, w.TAt, 1.f, 7.f, LMK, LMK, 256, 256, SM, SM, SM, SM, s);
        nt(1, w.Y, w.TAt, nullptr, w.TBt, 1.f, 15.f, LMK, LMK, 256, 256, SM, SM, 0, SM, s);
        nt(1, w.Y, w.TBt, nullptr, w.TAt, 1.f, 13.f, LMK, LMK, 256, 256, SM, SM, 0, SM, s);
        nt(2, Zc, w.TAt, Zn, Znt, 0.25f, 0.f, LMK, LMK, 256, 256, SM, SM, SM, SM, s);
        ushort* t;
        t = Zc; Zc = Zn; Zn = t;
        t = Zct; Zct = Znt; Znt = t;
    }
    // ---- attn3: S = q_l @ k^T (bf16), row stats, fused-softmax PV ----
    bt(1, w.ql, w.k, w.S, LMK, NPAD, 64, 64, 64, NPAD,
       (long long)LMK * 64, (long long)NPAD * 64, (long long)LMK * NPAD, BHN,
       nullptr, 0, nullptr, nullptr, nullptr, s);
    row_stats<<<BHN * LMK, 256, 0, s>>>(w.S, w.lm, w.li);
    pv_splitk<<<dim3(KSPL, 2, BHN), 256, 0, s>>>(w.S, w.vT, w.lm, w.li, w.o2p);
    reduce_o2<<<BHN * LMK * 64 / 256, 256, 0, s>>>(w.o2p, w.o2t);
    // Wt = (Zc @ o2)^T  (CT-only gemm_nt; Wt bh stride 128*256)
    nt(3, Zc, w.o2t, nullptr, w.Wt, 1.f, 0.f, LMK, 64, 256, 256,
       SM, 64 * 256, 0, 128 * 256, s);
    // ---- attn1 fused: softmax(q @ k_l^T) @ W -> ot ----
    attn1_fused<<<dim3(NPAD / 64, BHN), 256, 0, s>>>(w.q, w.kl, w.Wt, w.ot);
    // + depthwise conv(v)
    conv_add<<<dim3(NPAD / 64, BHN), 256, 0, s>>>(w.v, convw, w.ot);
    // out proj with fused residual: h += ot @ outw^T + outb
    bt(3, w.ot, outwb, h, 2 * NPAD, DIMC, DIMC, DIMC, DIMC, 0,
       0, 0, 0, 1, outb, 0, nullptr, nullptr, nullptr, s);
}

} // namespace

extern "C" void kernel_launch(void* const* d_in, const int* in_sizes, int n_in,
                              void* d_out, int out_size, void* d_ws, size_t ws_size,
                              hipStream_t stream)
{
    (void)in_sizes; (void)n_in; (void)out_size;
    const float* data  = (const float*)d_in[0];
    const float* w1    = (const float*)d_in[1];
    const float* b1    = (const float*)d_in[2];
    const float* cls   = (const float*)d_in[3];
    const float* ln1g  = (const float*)d_in[4];
    const float* ln1b  = (const float*)d_in[5];
    const float* qkv1w = (const float*)d_in[6];
    const float* out1w = (const float*)d_in[7];
    const float* out1b = (const float*)d_in[8];
    const float* conv1 = (const float*)d_in[9];
    const float* ln2g  = (const float*)d_in[10];
    const float* ln2b  = (const float*)d_in[11];
    const float* qkv2w = (const float*)d_in[12];
    const float* out2w = (const float*)d_in[13];
    const float* out2b = (const float*)d_in[14];
    const float* conv2 = (const float*)d_in[15];
    const float* lnfg  = (const float*)d_in[16];
    const float* lnfb  = (const float*)d_in[17];
    const float* w2    = (const float*)d_in[18];
    const float* b2    = (const float*)d_in[19];
    float* out = (float*)d_out;

    if (ws_size < 209473792ull) return;
    char* p = (char*)d_ws;
    auto alloc = [&](size_t bytes) { char* r = p; p += (bytes + 255) & ~(size_t)255; return r; };
    WS w;
    w.h     = (float*)alloc((size_t)2 * SEQ * DIMC * 4);
    w.xp    = (ushort*)alloc((size_t)2 * NPAD * DIMC * 2);
    w.q     = (ushort*)alloc((size_t)BHN * NPAD * 64 * 2);
    w.k     = (ushort*)alloc((size_t)BHN * NPAD * 64 * 2);   // ot overlay
    w.v     = (ushort*)alloc((size_t)BHN * NPAD * 64 * 2);
    w.vT    = (ushort*)alloc((size_t)BHN * 64 * NPAD * 2);
    w.ql    = (ushort*)alloc((size_t)BHN * LMK * 64 * 2);
    w.kl    = (ushort*)alloc((size_t)BHN * LMK * 64 * 2);
    w.scal  = (float*)alloc(256);
    w.lm    = (float*)alloc((size_t)BHN * LMK * 4);
    w.li    = (float*)alloc((size_t)BHN * LMK * 4);
    w.datab = (ushort*)alloc((size_t)2 * MPADR * 1024 * 2);
    w.w1b   = (ushort*)alloc((size_t)512 * 1024 * 2);
    w.qkvwb1= (ushort*)alloc((size_t)1536 * 512 * 2);
    w.qkvwb2= (ushort*)alloc((size_t)1536 * 512 * 2);
    w.outwb1= (ushort*)alloc((size_t)512 * 512 * 2);
    w.outwb2= (ushort*)alloc((size_t)512 * 512 * 2);
    w.X     = (ushort*)alloc((size_t)BHN * LMK * LMK * 2);
    w.Y     = (ushort*)alloc((size_t)BHN * LMK * LMK * 2);
    w.TAt   = (ushort*)alloc((size_t)BHN * LMK * LMK * 2);
    w.TBt   = (ushort*)alloc((size_t)BHN * LMK * LMK * 2);
    w.Z0    = (ushort*)alloc((size_t)BHN * LMK * LMK * 2);
    w.Z0t   = (ushort*)alloc((size_t)BHN * LMK * LMK * 2);
    w.Z1    = (ushort*)alloc((size_t)BHN * LMK * LMK * 2);
    w.Z1t   = (ushort*)alloc((size_t)BHN * LMK * LMK * 2);
    w.o2p   = (float*)alloc((size_t)KSPL * BHN * LMK * 64 * 4);
    w.o2t   = (ushort*)alloc((size_t)BHN * 64 * 256 * 2);
    w.Wt    = (ushort*)alloc((size_t)BHN * 128 * 256 * 2);
    w.S     = (ushort*)alloc((size_t)BHN * LMK * NPAD * 2);
    w.ot    = w.k;           // ot overlays k (k dead after attn3 score GEMM)

    // ---- one-time per-call bf16 conversions ----
    for (int b = 0; b < 2; ++b)
        cvt_bf16<<<3000, 256, 0, stream>>>(data + (size_t)b * 6000 * 1024,
                                           w.datab + (size_t)b * MPADR * 1024, 768000);
    cvt_bf16<<<256, 256, 0, stream>>>(w1, w.w1b, 65536);
    cvt_bf16<<<384, 256, 0, stream>>>(qkv1w, w.qkvwb1, 98304);
    cvt_bf16<<<384, 256, 0, stream>>>(qkv2w, w.qkvwb2, 98304);
    cvt_bf16<<<128, 256, 0, stream>>>(out1w, w.outwb1, 32768);
    cvt_bf16<<<128, 256, 0, stream>>>(out2w, w.outwb2, 32768);

    // fc1: h[b, 1+i, :] = relu(data[b,i,:] @ w1^T + b1)
    bt(0, w.datab, w.w1b, w.h + DIMC, 6000, DIMC, 1024, 1024, 1024, DIMC,
       (long long)MPADR * 1024, 0, (long long)SEQ * DIMC, 2, b1, 1,
       nullptr, nullptr, nullptr, stream);
    extend_h<<<dim3(85, 2), 256, 0, stream>>>(w.h, cls);

    nystrom_layer(w.h, ln1g, ln1b, w.qkvwb1, w.outwb1, out1b, conv1, w, stream);
    nystrom_layer(w.h, ln2g, ln2b, w.qkvwb2, w.outwb2, out2b, conv2, w, stream);

    final_head<<<2, 256, 0, stream>>>(w.h, lnfg, lnfb, w2, b2, out);
}